// Round 6
// baseline (147.869 us; speedup 1.0000x reference)
//
#include <hip/hip_runtime.h>
#include <stdint.h>

typedef __bf16 bf16x8 __attribute__((ext_vector_type(8)));
typedef float f32x4 __attribute__((ext_vector_type(4)));
typedef unsigned short ushort_t;
typedef unsigned int uint_t;

__device__ inline ushort_t f2bf(float f) {
  uint_t u = __builtin_bit_cast(uint_t, f);
  u = (u + 0x7FFFu + ((u >> 16) & 1u)) >> 16;
  return (ushort_t)u;
}

// async global->LDS, 16B per lane. LDS dest must be wave-uniform base; HW adds lane*16.
__device__ inline void gll16(const void* g, void* l) {
  __builtin_amdgcn_global_load_lds(
      (__attribute__((address_space(1))) void*)(uintptr_t)g,
      (__attribute__((address_space(3))) void*)(uint32_t)(uintptr_t)l,
      16, 0, 0);
}

__global__ void cast_bf16(const float* __restrict__ in, ushort_t* __restrict__ out,
                          int n4, float scale) {
  int i = blockIdx.x * blockDim.x + threadIdx.x;
  int st = gridDim.x * blockDim.x;
  for (; i < n4; i += st) {
    float4 v = reinterpret_cast<const float4*>(in)[i];
    ushort4 o;
    o.x = f2bf(v.x * scale);
    o.y = f2bf(v.y * scale);
    o.z = f2bf(v.z * scale);
    o.w = f2bf(v.w * scale);
    reinterpret_cast<ushort4*>(out)[i] = o;
  }
}

// All 4 weight matrices in one launch; out = Wq*s | Wk | Wv | Wo contiguous.
__global__ void cast_w4(const float* __restrict__ w0, const float* __restrict__ w1,
                        const float* __restrict__ w2, const float* __restrict__ w3,
                        ushort_t* __restrict__ out, float s0) {
  const int i = blockIdx.x * 256 + threadIdx.x;
  const int which = i >> 18;
  const float* src = which == 0 ? w0 : which == 1 ? w1 : which == 2 ? w2 : w3;
  const float sc = which == 0 ? s0 : 1.0f;
  float4 v = reinterpret_cast<const float4*>(src)[i & 0x3FFFF];
  ushort4 o;
  o.x = f2bf(v.x * sc);
  o.y = f2bf(v.y * sc);
  o.z = f2bf(v.z * sc);
  o.w = f2bf(v.w * sc);
  reinterpret_cast<ushort4*>(out)[i] = o;
}

// ---------------- 8-phase 256x256 GEMM: C[8192,3072] = A[8192,1024] * B[3072,1024]^T
#define MFMA16(A_, B_, C_) __builtin_amdgcn_mfma_f32_16x16x32_bf16(A_, B_, C_, 0, 0, 0)

// stage one operand tile half-pair: 4 gll16 (rows +0,+64,+128,+192), LDS linear.
#define STAGE_A(WBU, SK)                                              \
  gll16(gA + (SK), &smem[(WBU) + (w << 9)]);                          \
  gll16(gA + 65536 + (SK), &smem[(WBU) + 4096 + (w << 9)]);           \
  gll16(gA + 131072 + (SK), &smem[(WBU) + 8192 + (w << 9)]);          \
  gll16(gA + 196608 + (SK), &smem[(WBU) + 12288 + (w << 9)]);
#define STAGE_B(WBU, SK)                                              \
  gll16(gB + (SK), &smem[(WBU) + 16384 + (w << 9)]);                  \
  gll16(gB + 65536 + (SK), &smem[(WBU) + 20480 + (w << 9)]);          \
  gll16(gB + 131072 + (SK), &smem[(WBU) + 24576 + (w << 9)]);         \
  gll16(gB + 196608 + (SK), &smem[(WBU) + 28672 + (w << 9)]);

#define RD_A(RBU, mbase)                                                          \
  _Pragma("unroll") for (int m_ = 0; m_ < 4; ++m_) {                              \
    a[m_][0] = *(const bf16x8*)&smem[(RBU) + arowU + ((mbase + m_) << 10) + cxu0]; \
    a[m_][1] = *(const bf16x8*)&smem[(RBU) + arowU + ((mbase + m_) << 10) + cxu1]; \
  }
#define RD_B(RBU, breg, nbase)                                                      \
  _Pragma("unroll") for (int n_ = 0; n_ < 2; ++n_) {                                \
    breg[n_][0] = *(const bf16x8*)&smem[(RBU) + browU + ((nbase + n_) << 10) + cxu0]; \
    breg[n_][1] = *(const bf16x8*)&smem[(RBU) + browU + ((nbase + n_) << 10) + cxu1]; \
  }
#define MM(mbase, nbase, breg)                                                     \
  _Pragma("unroll") for (int m_ = 0; m_ < 4; ++m_) _Pragma("unroll") for (int n_ = \
                                                                              0;   \
                                                                          n_ < 2;  \
                                                                          ++n_) {  \
    acc[mbase + m_][nbase + n_] =                                                  \
        MFMA16(a[m_][0], breg[n_][0], acc[mbase + m_][nbase + n_]);                \
    acc[mbase + m_][nbase + n_] =                                                  \
        MFMA16(a[m_][1], breg[n_][1], acc[mbase + m_][nbase + n_]);                \
  }

// One K-tile (BK=64), 4 phases. RBU/WBU = u16 base of read/write LDS buffer.
// PF literal: stages tile(SK) and uses counted vmcnt(4); last tile drains.
#define TILE(RBU, WBU, SK, PF)                                                \
  {                                                                           \
    if (PF) { STAGE_A(WBU, SK) }                                              \
    if (PF) {                                                                 \
      asm volatile("s_waitcnt vmcnt(4)" ::: "memory");                        \
    } else {                                                                  \
      asm volatile("s_waitcnt vmcnt(0)" ::: "memory");                        \
    }                                                                         \
    __builtin_amdgcn_s_barrier();                                             \
    RD_A(RBU, 0);                                                             \
    RD_B(RBU, b0, 0);                                                         \
    asm volatile("s_waitcnt lgkmcnt(0)" ::: "memory");                        \
    __builtin_amdgcn_s_setprio(1);                                            \
    MM(0, 0, b0);                                                             \
    __builtin_amdgcn_s_setprio(0);                                            \
    __builtin_amdgcn_s_barrier();                                             \
    RD_B(RBU, b1, 2);                                                         \
    if (PF) { STAGE_B(WBU, SK) }                                              \
    __builtin_amdgcn_s_barrier();                                             \
    asm volatile("s_waitcnt lgkmcnt(0)" ::: "memory");                        \
    __builtin_amdgcn_s_setprio(1);                                            \
    MM(0, 2, b1);                                                             \
    __builtin_amdgcn_s_setprio(0);                                            \
    __builtin_amdgcn_s_barrier();                                             \
    RD_A(RBU, 4);                                                             \
    __builtin_amdgcn_s_barrier();                                             \
    asm volatile("s_waitcnt lgkmcnt(0)" ::: "memory");                        \
    __builtin_amdgcn_s_setprio(1);                                            \
    MM(4, 2, b1);                                                             \
    __builtin_amdgcn_s_setprio(0);                                            \
    __builtin_amdgcn_s_barrier();                                             \
    __builtin_amdgcn_s_setprio(1);                                            \
    MM(4, 0, b0);                                                             \
    __builtin_amdgcn_s_setprio(0);                                            \
    __builtin_amdgcn_s_barrier();                                             \
  }

__global__ __launch_bounds__(512, 2) void gemm256_qkv(const ushort_t* __restrict__ A,
                                                      const ushort_t* __restrict__ B,
                                                      ushort_t* __restrict__ C) {
  // LDS: 2 bufs x (A 16384 u16 | B 16384 u16) = 128 KiB.
  __shared__ __attribute__((aligned(16))) ushort_t smem[65536];
  const int tid = threadIdx.x;
  const int lane = tid & 63;
  const int w = tid >> 6;
  const int wm = w >> 2, wn = w & 3;

  // XCD-aware swizzle (384 % 8 == 0 -> bijective); row-major tiles: 4 A-panels/XCD.
  const int bid = blockIdx.x;
  const int swz = (bid & 7) * 48 + (bid >> 3);
  const int m0 = (swz / 12) * 256;
  const int n0 = (swz % 12) * 256;

  // staging: thread covers phys 16B chunk c=tid (+512); pre-swizzled source col.
  const int scol = ((tid & 7) ^ ((tid >> 3) & 7)) * 8;
  const ushort_t* gA = A + (size_t)(m0 + (tid >> 3)) * 1024 + scol;
  const ushort_t* gB = B + (size_t)(n0 + (tid >> 3)) * 1024 + scol;

  // read offsets (u16 units): phys = row*64 + ((kk*32 + hi*8) ^ ((lane&7)*8))
  const int lr = lane & 15;
  const int hi = lane >> 4;
  const int arowU = (wm * 128 + lr) * 64;
  const int browU = 16384 + (wn * 64 + lr) * 64;
  const int cxu0 = (hi * 8) ^ ((lane & 7) << 3);
  const int cxu1 = (32 + hi * 8) ^ ((lane & 7) << 3);

  f32x4 acc[8][4] = {};
  bf16x8 a[4][2], b0[2][2], b1[2][2];

  // prologue: stage tile 0 into buf0
  STAGE_A(0, 0)
  STAGE_B(0, 0)

  int sk = 64;
  for (int it = 0; it < 7; ++it) {
    TILE(0, 32768, sk, true) sk += 64;      // even tile: read buf0, stage buf1
    TILE(32768, 0, sk, true) sk += 64;      // odd tile
  }
  TILE(0, 32768, sk, true)                  // t=14 stages tile 15
  TILE(32768, 0, 0, false)                  // t=15: drain, no stage

  const size_t erow = (size_t)(m0 + wm * 128 + hi * 4);
  const int ecol = n0 + wn * 64 + lr;
#pragma unroll
  for (int mf = 0; mf < 8; ++mf)
#pragma unroll
    for (int nf = 0; nf < 4; ++nf)
#pragma unroll
      for (int r = 0; r < 4; ++r)
        C[(erow + mf * 16 + r) * 3072 + ecol + nf * 16] = f2bf(acc[mf][nf][r]);
}

// ---------------- m97-style 128x128 GEMM (kept for the out-projection)
template <bool F32OUT>
__global__ __launch_bounds__(256) void gemm_bt(const ushort_t* __restrict__ A,
                                               const ushort_t* __restrict__ B,
                                               void* __restrict__ C, int M, int N, int K) {
  __shared__ __attribute__((aligned(16))) ushort_t As[128 * 32];
  __shared__ __attribute__((aligned(16))) ushort_t Bs[128 * 32];
  const int tid = threadIdx.x;
  const int lane = tid & 63;
  const int w = tid >> 6;
  const int wr = w >> 1, wc = w & 1;
  const int m0 = blockIdx.x * 128, n0 = blockIdx.y * 128;
  const int lr = lane & 15;
  const int lk = (lane >> 4) << 3;

  f32x4 acc[4][4] = {};

  const int srow = tid >> 2;
  const int scol = (tid & 3) << 3;
  const ushort_t* gA0 = A + (size_t)(m0 + srow) * K + scol;
  const ushort_t* gB0 = B + (size_t)(n0 + srow) * K + scol;
  const size_t rstep = (size_t)64 * K;
  ushort_t* lA0 = &As[(tid & 0xC0) * 8];
  ushort_t* lA1 = lA0 + 2048;
  ushort_t* lB0 = &Bs[(tid & 0xC0) * 8];
  ushort_t* lB1 = lB0 + 2048;

  for (int k0 = 0; k0 < K; k0 += 32) {
    gll16(gA0 + k0, lA0);
    gll16(gA0 + rstep + k0, lA1);
    gll16(gB0 + k0, lB0);
    gll16(gB0 + rstep + k0, lB1);
    __syncthreads();
    bf16x8 a[4], bb[4];
#pragma unroll
    for (int i = 0; i < 4; ++i)
      a[i] = *reinterpret_cast<const bf16x8*>(&As[(wr * 64 + i * 16 + lr) * 32 + lk]);
#pragma unroll
    for (int j = 0; j < 4; ++j)
      bb[j] = *reinterpret_cast<const bf16x8*>(&Bs[(wc * 64 + j * 16 + lr) * 32 + lk]);
#pragma unroll
    for (int i = 0; i < 4; ++i)
#pragma unroll
      for (int j = 0; j < 4; ++j)
        acc[i][j] = __builtin_amdgcn_mfma_f32_16x16x32_bf16(a[i], bb[j], acc[i][j], 0, 0, 0);
    __syncthreads();
  }

  const int orow = m0 + wr * 64 + ((lane >> 4) << 2);
  const int ocol = n0 + wc * 64 + lr;
#pragma unroll
  for (int i = 0; i < 4; ++i)
#pragma unroll
    for (int j = 0; j < 4; ++j)
#pragma unroll
      for (int r = 0; r < 4; ++r) {
        const size_t idx = (size_t)(orow + i * 16 + r) * N + (ocol + j * 16);
        if (F32OUT)
          ((float*)C)[idx] = acc[i][j][r];
        else
          ((ushort_t*)C)[idx] = f2bf(acc[i][j][r]);
      }
}

// Causal flash attention. QKV [8192,3072] bf16 (Q|K|V), Q pre-scaled by 0.125*log2(e).
__global__ __launch_bounds__(256, 2) void attn_fwd(const ushort_t* __restrict__ QKV,
                                                   ushort_t* __restrict__ ctx) {
  const int bid = blockIdx.x;
  const int h = bid & 15;
  const int b = (bid >> 4) & 7;
  const int p = bid >> 7;
  const int tid = threadIdx.x;
  const int lane = tid & 63;
  const int w = tid >> 6;
  const int lr = lane & 15;
  const int lg = lane >> 4;
  const int dk = lg << 3;

  __shared__ __attribute__((aligned(16))) ushort_t Ks[64 * 72];
  __shared__ __attribute__((aligned(16))) uint_t VtDw[64 * 36];
  __shared__ __attribute__((aligned(16))) ushort_t Pl[4][32 * 72];

  const int kkey = tid >> 2, kdg = tid & 3;
  const int vkp = tid & 31, vdg = tid >> 5;
  const ushort_t* kgbase =
      QKV + ((size_t)(b * 1024 + kkey)) * 3072 + 1024 + h * 64 + kdg * 16;
  const ushort_t* vgbase =
      QKV + ((size_t)(b * 1024 + 2 * vkp)) * 3072 + 2048 + h * 64 + vdg * 8;

  const float FMAX2 = 23.083120654223414f;  // 16 * log2(e)

  for (int pi = 0; pi < 2; ++pi) {
    const int qt = pi ? (7 - p) : p;
    const int q0 = qt << 7;
    const int nt = (qt + 1) << 1;
    const int wrow0 = q0 + w * 32;

    bf16x8 qf[2][2];
#pragma unroll
    for (int i = 0; i < 2; ++i) {
      const ushort_t* qp =
          QKV + ((size_t)(b * 1024 + wrow0 + i * 16 + lr)) * 3072 + h * 64 + dk;
      qf[i][0] = *reinterpret_cast<const bf16x8*>(qp);
      qf[i][1] = *reinterpret_cast<const bf16x8*>(qp + 32);
    }

    f32x4 o[2][4] = {};
    float lsum[2] = {0.f, 0.f};

    uint4 rk0 = *reinterpret_cast<const uint4*>(kgbase);
    uint4 rk1 = *reinterpret_cast<const uint4*>(kgbase + 8);
    uint4 rv0 = *reinterpret_cast<const uint4*>(vgbase);
    uint4 rv1 = *reinterpret_cast<const uint4*>(vgbase + 3072);

    for (int t = 0; t < nt; ++t) {
      __syncthreads();
      {
        uint_t* kd = reinterpret_cast<uint_t*>(&Ks[kkey * 72 + kdg * 16]);
        *reinterpret_cast<uint4*>(kd) = rk0;
        *reinterpret_cast<uint4*>(kd + 4) = rk1;
        const ushort_t* e0 = reinterpret_cast<const ushort_t*>(&rv0);
        const ushort_t* e1 = reinterpret_cast<const ushort_t*>(&rv1);
#pragma unroll
        for (int j = 0; j < 8; ++j)
          VtDw[(vdg * 8 + j) * 36 + vkp] = (uint_t)e0[j] | ((uint_t)e1[j] << 16);
      }
      __syncthreads();

      if (t + 1 < nt) {
        const size_t off = (size_t)(t + 1) * 64 * 3072;
        rk0 = *reinterpret_cast<const uint4*>(kgbase + off);
        rk1 = *reinterpret_cast<const uint4*>(kgbase + off + 8);
        rv0 = *reinterpret_cast<const uint4*>(vgbase + off);
        rv1 = *reinterpret_cast<const uint4*>(vgbase + off + 3072);
      }

      const int kb = t << 6;
      if (kb > wrow0 + 31) continue;

      bf16x8 kf0[4], kf1[4];
#pragma unroll
      for (int f = 0; f < 4; ++f) {
        kf0[f] = *reinterpret_cast<const bf16x8*>(&Ks[(f * 16 + lr) * 72 + dk]);
        kf1[f] = *reinterpret_cast<const bf16x8*>(&Ks[(f * 16 + lr) * 72 + 32 + dk]);
      }
      f32x4 s[2][4];
#pragma unroll
      for (int i = 0; i < 2; ++i)
#pragma unroll
        for (int f = 0; f < 4; ++f) {
          f32x4 z = {0.f, 0.f, 0.f, 0.f};
          z = __builtin_amdgcn_mfma_f32_16x16x32_bf16(kf0[f], qf[i][0], z, 0, 0, 0);
          s[i][f] = __builtin_amdgcn_mfma_f32_16x16x32_bf16(kf1[f], qf[i][1], z, 0, 0, 0);
        }

      const bool needmask = (kb + 63 > wrow0);
#pragma unroll
      for (int i = 0; i < 2; ++i) {
        const int qr = wrow0 + i * 16 + lr;
#pragma unroll
        for (int f = 0; f < 4; ++f) {
          const int kbase = kb + f * 16 + (lg << 2);
          float p0 = __builtin_amdgcn_exp2f(s[i][f][0] - FMAX2);
          float p1 = __builtin_amdgcn_exp2f(s[i][f][1] - FMAX2);
          float p2 = __builtin_amdgcn_exp2f(s[i][f][2] - FMAX2);
          float p3 = __builtin_amdgcn_exp2f(s[i][f][3] - FMAX2);
          if (needmask) {
            p0 = (kbase + 0 <= qr) ? p0 : 0.f;
            p1 = (kbase + 1 <= qr) ? p1 : 0.f;
            p2 = (kbase + 2 <= qr) ? p2 : 0.f;
            p3 = (kbase + 3 <= qr) ? p3 : 0.f;
          }
          lsum[i] += (p0 + p1) + (p2 + p3);
          ushort4 pk = {f2bf(p0), f2bf(p1), f2bf(p2), f2bf(p3)};
          *reinterpret_cast<ushort4*>(
              &Pl[w][(i * 16 + lr) * 72 + f * 16 + (lg << 2)]) = pk;
        }
      }

      bf16x8 vb[2][4];
#pragma unroll
      for (int kblk = 0; kblk < 2; ++kblk)
#pragma unroll
        for (int fh = 0; fh < 4; ++fh)
          vb[kblk][fh] = *reinterpret_cast<const bf16x8*>(
              &VtDw[(fh * 16 + lr) * 36 + kblk * 16 + (lg << 2)]);
#pragma unroll
      for (int i = 0; i < 2; ++i)
#pragma unroll
        for (int kblk = 0; kblk < 2; ++kblk) {
          const bf16x8 pa = *reinterpret_cast<const bf16x8*>(
              &Pl[w][(i * 16 + lr) * 72 + kblk * 32 + dk]);
#pragma unroll
          for (int fh = 0; fh < 4; ++fh)
            o[i][fh] = __builtin_amdgcn_mfma_f32_16x16x32_bf16(pa, vb[kblk][fh],
                                                               o[i][fh], 0, 0, 0);
        }
    }

#pragma unroll
    for (int i = 0; i < 2; ++i) {
      float ls = lsum[i];
      ls += __shfl_xor(ls, 16);
      ls += __shfl_xor(ls, 32);
      const float linv = 1.0f / ls;
      const size_t crow = (size_t)(b * 1024 + wrow0 + i * 16 + (lg << 2));
#pragma unroll
      for (int r = 0; r < 4; ++r) {
        const float li = __shfl(linv, (lg << 2) + r);
#pragma unroll
        for (int fh = 0; fh < 4; ++fh)
          ctx[(crow + r) * 1024 + h * 64 + fh * 16 + lr] = f2bf(o[i][fh][r] * li);
      }
    }
  }
}

extern "C" void kernel_launch(void* const* d_in, const int* in_sizes, int n_in,
                              void* d_out, int out_size, void* d_ws, size_t ws_size,
                              hipStream_t stream) {
  const float* x = (const float*)d_in[0];
  const float* Wk = (const float*)d_in[1];
  const float* Wq = (const float*)d_in[2];
  const float* Wv = (const float*)d_in[3];
  const float* Wo = (const float*)d_in[4];

  char* ws = (char*)d_ws;
  ushort_t* xb = (ushort_t*)ws;                  // [8192,1024] bf16 (reused as ctx)
  ushort_t* Wc = (ushort_t*)(ws + (16u << 20));  // Wq*0.125*log2e | Wk | Wv | Wo
  ushort_t* Wob = Wc + 3u * 1024 * 1024;
  ushort_t* QKV = (ushort_t*)(ws + (24u << 20));  // [8192,3072] bf16
  ushort_t* ctx = xb;

  cast_bf16<<<2048, 256, 0, stream>>>(x, xb, (8192 * 1024) / 4, 1.0f);
  cast_w4<<<4096, 256, 0, stream>>>(Wq, Wk, Wv, Wo, Wc, 0.125f * 1.4426950408889634f);

  gemm256_qkv<<<384, 512, 0, stream>>>(xb, Wc, QKV);

  attn_fwd<<<512, 256, 0, stream>>>(QKV, ctx);

  dim3 g2(64, 8);
  gemm_bt<true><<<g2, 256, 0, stream>>>(ctx, Wob, (float*)d_out, 8192, 1024, 1024);
}

// Round 7
// 138.583 us; speedup vs baseline: 1.0670x; 1.0670x over previous
//
#include <hip/hip_runtime.h>
#include <stdint.h>

typedef __bf16 bf16x8 __attribute__((ext_vector_type(8)));
typedef float f32x4 __attribute__((ext_vector_type(4)));
typedef unsigned short ushort_t;
typedef unsigned int uint_t;

__device__ inline ushort_t f2bf(float f) {
  uint_t u = __builtin_bit_cast(uint_t, f);
  u = (u + 0x7FFFu + ((u >> 16) & 1u)) >> 16;
  return (ushort_t)u;
}

// async global->LDS, 16B per lane. LDS dest must be wave-uniform base; HW adds lane*16.
__device__ inline void gll16(const void* g, void* l) {
  __builtin_amdgcn_global_load_lds(
      (__attribute__((address_space(1))) void*)(uintptr_t)g,
      (__attribute__((address_space(3))) void*)(uint32_t)(uintptr_t)l,
      16, 0, 0);
}

__global__ void cast_bf16(const float* __restrict__ in, ushort_t* __restrict__ out,
                          int n4, float scale) {
  int i = blockIdx.x * blockDim.x + threadIdx.x;
  int st = gridDim.x * blockDim.x;
  for (; i < n4; i += st) {
    float4 v = reinterpret_cast<const float4*>(in)[i];
    ushort4 o;
    o.x = f2bf(v.x * scale);
    o.y = f2bf(v.y * scale);
    o.z = f2bf(v.z * scale);
    o.w = f2bf(v.w * scale);
    reinterpret_cast<ushort4*>(out)[i] = o;
  }
}

// All 4 weight matrices in one launch; out = Wq*s | Wk | Wv | Wo contiguous.
__global__ void cast_w4(const float* __restrict__ w0, const float* __restrict__ w1,
                        const float* __restrict__ w2, const float* __restrict__ w3,
                        ushort_t* __restrict__ out, float s0) {
  const int i = blockIdx.x * 256 + threadIdx.x;
  const int which = i >> 18;
  const float* src = which == 0 ? w0 : which == 1 ? w1 : which == 2 ? w2 : w3;
  const float sc = which == 0 ? s0 : 1.0f;
  float4 v = reinterpret_cast<const float4*>(src)[i & 0x3FFFF];
  ushort4 o;
  o.x = f2bf(v.x * sc);
  o.y = f2bf(v.y * sc);
  o.z = f2bf(v.z * sc);
  o.w = f2bf(v.w * sc);
  reinterpret_cast<ushort4*>(out)[i] = o;
}

// ---------------- 8-wave counted-vmcnt GEMM template: C = A[8192,1024] * B[N,1024]^T
// MF/NF = per-wave m/n fragment counts (wave tile = MF*16 x NF*16), 8 waves as 2x4.
// BM = MF*32, BN = NF*64. LDS double-buffered, T2 XOR-swizzle both sides, T5 setprio.
#define MFMA16(A_, B_, C_) __builtin_amdgcn_mfma_f32_16x16x32_bf16(A_, B_, C_, 0, 0, 0)

template <int MF, int NF, int NTN, int LDC, bool F32OUT>
__global__ __launch_bounds__(512, 2) void gemm8p(const ushort_t* __restrict__ A,
                                                 const ushort_t* __restrict__ B,
                                                 void* __restrict__ C) {
  constexpr int BM = MF * 32;
  constexpr int BN = NF * 64;
  constexpr int NA = BM / 64;        // gll16 per thread for A-tile
  constexpr int NB = BN / 64;        // gll16 per thread for B-tile
  constexpr int AU = BM * 64;        // u16 per A buffer
  constexpr int BUF = AU + BN * 64;  // u16 per (A|B) buffer
  constexpr int NWG = (8192 / BM) * NTN;
  __shared__ __attribute__((aligned(16))) ushort_t smem[2 * BUF];

  const int tid = threadIdx.x;
  const int lane = tid & 63;
  const int w = tid >> 6;
  const int wm = w >> 2, wn = w & 3;

  // XCD-aware bijective swizzle (NWG % 8 == 0), row-major tiles.
  const int bid = blockIdx.x;
  const int swz = (bid & 7) * (NWG / 8) + (bid >> 3);
  const int m0 = (swz / NTN) * BM;
  const int n0 = (swz % NTN) * BN;

  // staging: thread covers row (tid>>3), phys 16B chunk (tid&7); source col
  // pre-swizzled so phys LDS stays linear (rule #21: same involution both sides).
  const int scol = ((tid & 7) ^ ((tid >> 3) & 7)) * 8;
  const ushort_t* gA = A + (size_t)(m0 + (tid >> 3)) * 1024 + scol;
  const ushort_t* gB = B + (size_t)(n0 + (tid >> 3)) * 1024 + scol;

  // read offsets (u16 units): row*64 + ((k-chunk)*8 ^ (row&7)*8)
  const int lr = lane & 15;
  const int hi = lane >> 4;
  const int arow = (wm * MF * 16 + lr) * 64;
  const int brow = AU + (wn * NF * 16 + lr) * 64;
  const int cx0 = (hi * 8) ^ ((lane & 7) << 3);
  const int cx1 = cx0 ^ 32;

  f32x4 acc[MF][NF] = {};
  bf16x8 a[MF / 2][2], b[NF][2];

  auto stageA = [&](int wbu, int sk) __attribute__((always_inline)) {
#pragma unroll
    for (int i = 0; i < NA; ++i)
      gll16(gA + i * 65536 + sk, &smem[wbu + i * 4096 + (w << 9)]);
  };
  auto stageB = [&](int wbu, int sk) __attribute__((always_inline)) {
#pragma unroll
    for (int i = 0; i < NB; ++i)
      gll16(gB + i * 65536 + sk, &smem[wbu + AU + i * 4096 + (w << 9)]);
  };
  auto rdA = [&](int rbu, int mbase) __attribute__((always_inline)) {
#pragma unroll
    for (int m = 0; m < MF / 2; ++m) {
      const int base = rbu + arow + (mbase + m) * 1024;
      a[m][0] = *(const bf16x8*)&smem[base + cx0];
      a[m][1] = *(const bf16x8*)&smem[base + cx1];
    }
  };
  auto rdB = [&](int rbu) __attribute__((always_inline)) {
#pragma unroll
    for (int n = 0; n < NF; ++n) {
      const int base = rbu + brow + n * 1024;
      b[n][0] = *(const bf16x8*)&smem[base + cx0];
      b[n][1] = *(const bf16x8*)&smem[base + cx1];
    }
  };
  auto mm = [&](int mbase) __attribute__((always_inline)) {
#pragma unroll
    for (int m = 0; m < MF / 2; ++m)
#pragma unroll
      for (int n = 0; n < NF; ++n) {
        acc[mbase + m][n] = MFMA16(a[m][0], b[n][0], acc[mbase + m][n]);
        acc[mbase + m][n] = MFMA16(a[m][1], b[n][1], acc[mbase + m][n]);
      }
  };

  // One K-tile (BK=64): 2 phases, 4 barriers, counted vmcnt (never 0 mid-loop).
  auto tile = [&](int rbu, int wbu, int sk, bool pf) __attribute__((always_inline)) {
    if (pf) {
      stageA(wbu, sk);
      if constexpr (MF == 8)
        asm volatile("s_waitcnt vmcnt(4)" ::: "memory");
      else
        asm volatile("s_waitcnt vmcnt(2)" ::: "memory");
    } else {
      asm volatile("s_waitcnt vmcnt(0)" ::: "memory");
    }
    __builtin_amdgcn_s_barrier();
    rdA(rbu, 0);
    rdB(rbu);
    asm volatile("s_waitcnt lgkmcnt(0)" ::: "memory");
    __builtin_amdgcn_s_setprio(1);
    mm(0);
    __builtin_amdgcn_s_setprio(0);
    __builtin_amdgcn_s_barrier();
    rdA(rbu, MF / 2);
    if (pf) stageB(wbu, sk);
    __builtin_amdgcn_s_barrier();
    asm volatile("s_waitcnt lgkmcnt(0)" ::: "memory");
    __builtin_amdgcn_s_setprio(1);
    mm(MF / 2);
    __builtin_amdgcn_s_setprio(0);
    __builtin_amdgcn_s_barrier();
  };

  stageA(0, 0);
  stageB(0, 0);
  int sk = 64;
  for (int it = 0; it < 7; ++it) {
    tile(0, BUF, sk, true);
    sk += 64;
    tile(BUF, 0, sk, true);
    sk += 64;
  }
  tile(0, BUF, sk, true);   // t=14 stages tile 15
  tile(BUF, 0, 0, false);   // t=15: drain

  const size_t erow = (size_t)(m0 + wm * MF * 16 + hi * 4);
  const int ecol = n0 + wn * NF * 16 + lr;
#pragma unroll
  for (int mf = 0; mf < MF; ++mf)
#pragma unroll
    for (int nf = 0; nf < NF; ++nf)
#pragma unroll
      for (int r = 0; r < 4; ++r) {
        const size_t idx = (erow + mf * 16 + r) * LDC + ecol + nf * 16;
        if constexpr (F32OUT)
          ((float*)C)[idx] = acc[mf][nf][r];
        else
          ((ushort_t*)C)[idx] = f2bf(acc[mf][nf][r]);
      }
}

// Causal flash attention. QKV [8192,3072] bf16 (Q|K|V), Q pre-scaled by 0.125*log2(e).
__global__ __launch_bounds__(256, 2) void attn_fwd(const ushort_t* __restrict__ QKV,
                                                   ushort_t* __restrict__ ctx) {
  const int bid = blockIdx.x;
  const int h = bid & 15;
  const int b = (bid >> 4) & 7;
  const int p = bid >> 7;
  const int tid = threadIdx.x;
  const int lane = tid & 63;
  const int w = tid >> 6;
  const int lr = lane & 15;
  const int lg = lane >> 4;
  const int dk = lg << 3;

  __shared__ __attribute__((aligned(16))) ushort_t Ks[64 * 72];
  __shared__ __attribute__((aligned(16))) uint_t VtDw[64 * 36];
  __shared__ __attribute__((aligned(16))) ushort_t Pl[4][32 * 72];

  const int kkey = tid >> 2, kdg = tid & 3;
  const int vkp = tid & 31, vdg = tid >> 5;
  const ushort_t* kgbase =
      QKV + ((size_t)(b * 1024 + kkey)) * 3072 + 1024 + h * 64 + kdg * 16;
  const ushort_t* vgbase =
      QKV + ((size_t)(b * 1024 + 2 * vkp)) * 3072 + 2048 + h * 64 + vdg * 8;

  const float FMAX2 = 23.083120654223414f;  // 16 * log2(e)

  for (int pi = 0; pi < 2; ++pi) {
    const int qt = pi ? (7 - p) : p;
    const int q0 = qt << 7;
    const int nt = (qt + 1) << 1;
    const int wrow0 = q0 + w * 32;

    bf16x8 qf[2][2];
#pragma unroll
    for (int i = 0; i < 2; ++i) {
      const ushort_t* qp =
          QKV + ((size_t)(b * 1024 + wrow0 + i * 16 + lr)) * 3072 + h * 64 + dk;
      qf[i][0] = *reinterpret_cast<const bf16x8*>(qp);
      qf[i][1] = *reinterpret_cast<const bf16x8*>(qp + 32);
    }

    f32x4 o[2][4] = {};
    float lsum[2] = {0.f, 0.f};

    uint4 rk0 = *reinterpret_cast<const uint4*>(kgbase);
    uint4 rk1 = *reinterpret_cast<const uint4*>(kgbase + 8);
    uint4 rv0 = *reinterpret_cast<const uint4*>(vgbase);
    uint4 rv1 = *reinterpret_cast<const uint4*>(vgbase + 3072);

    for (int t = 0; t < nt; ++t) {
      __syncthreads();
      {
        uint_t* kd = reinterpret_cast<uint_t*>(&Ks[kkey * 72 + kdg * 16]);
        *reinterpret_cast<uint4*>(kd) = rk0;
        *reinterpret_cast<uint4*>(kd + 4) = rk1;
        const ushort_t* e0 = reinterpret_cast<const ushort_t*>(&rv0);
        const ushort_t* e1 = reinterpret_cast<const ushort_t*>(&rv1);
#pragma unroll
        for (int j = 0; j < 8; ++j)
          VtDw[(vdg * 8 + j) * 36 + vkp] = (uint_t)e0[j] | ((uint_t)e1[j] << 16);
      }
      __syncthreads();

      if (t + 1 < nt) {
        const size_t off = (size_t)(t + 1) * 64 * 3072;
        rk0 = *reinterpret_cast<const uint4*>(kgbase + off);
        rk1 = *reinterpret_cast<const uint4*>(kgbase + off + 8);
        rv0 = *reinterpret_cast<const uint4*>(vgbase + off);
        rv1 = *reinterpret_cast<const uint4*>(vgbase + off + 3072);
      }

      const int kb = t << 6;
      if (kb > wrow0 + 31) continue;

      bf16x8 kf0[4], kf1[4];
#pragma unroll
      for (int f = 0; f < 4; ++f) {
        kf0[f] = *reinterpret_cast<const bf16x8*>(&Ks[(f * 16 + lr) * 72 + dk]);
        kf1[f] = *reinterpret_cast<const bf16x8*>(&Ks[(f * 16 + lr) * 72 + 32 + dk]);
      }
      f32x4 s[2][4];
#pragma unroll
      for (int i = 0; i < 2; ++i)
#pragma unroll
        for (int f = 0; f < 4; ++f) {
          f32x4 z = {0.f, 0.f, 0.f, 0.f};
          z = __builtin_amdgcn_mfma_f32_16x16x32_bf16(kf0[f], qf[i][0], z, 0, 0, 0);
          s[i][f] = __builtin_amdgcn_mfma_f32_16x16x32_bf16(kf1[f], qf[i][1], z, 0, 0, 0);
        }

      const bool needmask = (kb + 63 > wrow0);
#pragma unroll
      for (int i = 0; i < 2; ++i) {
        const int qr = wrow0 + i * 16 + lr;
#pragma unroll
        for (int f = 0; f < 4; ++f) {
          const int kbase = kb + f * 16 + (lg << 2);
          float p0 = __builtin_amdgcn_exp2f(s[i][f][0] - FMAX2);
          float p1 = __builtin_amdgcn_exp2f(s[i][f][1] - FMAX2);
          float p2 = __builtin_amdgcn_exp2f(s[i][f][2] - FMAX2);
          float p3 = __builtin_amdgcn_exp2f(s[i][f][3] - FMAX2);
          if (needmask) {
            p0 = (kbase + 0 <= qr) ? p0 : 0.f;
            p1 = (kbase + 1 <= qr) ? p1 : 0.f;
            p2 = (kbase + 2 <= qr) ? p2 : 0.f;
            p3 = (kbase + 3 <= qr) ? p3 : 0.f;
          }
          lsum[i] += (p0 + p1) + (p2 + p3);
          ushort4 pk = {f2bf(p0), f2bf(p1), f2bf(p2), f2bf(p3)};
          *reinterpret_cast<ushort4*>(
              &Pl[w][(i * 16 + lr) * 72 + f * 16 + (lg << 2)]) = pk;
        }
      }

      bf16x8 vb[2][4];
#pragma unroll
      for (int kblk = 0; kblk < 2; ++kblk)
#pragma unroll
        for (int fh = 0; fh < 4; ++fh)
          vb[kblk][fh] = *reinterpret_cast<const bf16x8*>(
              &VtDw[(fh * 16 + lr) * 36 + kblk * 16 + (lg << 2)]);
#pragma unroll
      for (int i = 0; i < 2; ++i)
#pragma unroll
        for (int kblk = 0; kblk < 2; ++kblk) {
          const bf16x8 pa = *reinterpret_cast<const bf16x8*>(
              &Pl[w][(i * 16 + lr) * 72 + kblk * 32 + dk]);
#pragma unroll
          for (int fh = 0; fh < 4; ++fh)
            o[i][fh] = __builtin_amdgcn_mfma_f32_16x16x32_bf16(pa, vb[kblk][fh],
                                                               o[i][fh], 0, 0, 0);
        }
    }

#pragma unroll
    for (int i = 0; i < 2; ++i) {
      float ls = lsum[i];
      ls += __shfl_xor(ls, 16);
      ls += __shfl_xor(ls, 32);
      const float linv = 1.0f / ls;
      const size_t crow = (size_t)(b * 1024 + wrow0 + i * 16 + (lg << 2));
#pragma unroll
      for (int r = 0; r < 4; ++r) {
        const float li = __shfl(linv, (lg << 2) + r);
#pragma unroll
        for (int fh = 0; fh < 4; ++fh)
          ctx[(crow + r) * 1024 + h * 64 + fh * 16 + lr] = f2bf(o[i][fh][r] * li);
      }
    }
  }
}

extern "C" void kernel_launch(void* const* d_in, const int* in_sizes, int n_in,
                              void* d_out, int out_size, void* d_ws, size_t ws_size,
                              hipStream_t stream) {
  const float* x = (const float*)d_in[0];
  const float* Wk = (const float*)d_in[1];
  const float* Wq = (const float*)d_in[2];
  const float* Wv = (const float*)d_in[3];
  const float* Wo = (const float*)d_in[4];

  char* ws = (char*)d_ws;
  ushort_t* xb = (ushort_t*)ws;                  // [8192,1024] bf16 (reused as ctx)
  ushort_t* Wc = (ushort_t*)(ws + (16u << 20));  // Wq*0.125*log2e | Wk | Wv | Wo
  ushort_t* Wob = Wc + 3u * 1024 * 1024;
  ushort_t* QKV = (ushort_t*)(ws + (24u << 20));  // [8192,3072] bf16
  ushort_t* ctx = xb;

  cast_bf16<<<2048, 256, 0, stream>>>(x, xb, (8192 * 1024) / 4, 1.0f);
  cast_w4<<<4096, 256, 0, stream>>>(Wq, Wk, Wv, Wo, Wc, 0.125f * 1.4426950408889634f);

  // QKV: [8192,3072] = xb * Wc^T.  BM=256, BN=192 -> 512 blocks = 2 full rounds.
  gemm8p<8, 3, 16, 3072, false><<<512, 512, 0, stream>>>(xb, Wc, QKV);

  attn_fwd<<<512, 256, 0, stream>>>(QKV, ctx);

  // Out-proj: [8192,1024] = ctx * Wo^T.  BM=128, BN=256 -> 256 blocks = 1 full round.
  gemm8p<4, 4, 4, 1024, true><<<256, 512, 0, stream>>>(ctx, Wob, (float*)d_out);
}

// Round 8
// 137.305 us; speedup vs baseline: 1.0769x; 1.0093x over previous
//
#include <hip/hip_runtime.h>
#include <stdint.h>

typedef __bf16 bf16x8 __attribute__((ext_vector_type(8)));
typedef float f32x4 __attribute__((ext_vector_type(4)));
typedef unsigned short ushort_t;
typedef unsigned int uint_t;

__device__ inline ushort_t f2bf(float f) {
  uint_t u = __builtin_bit_cast(uint_t, f);
  u = (u + 0x7FFFu + ((u >> 16) & 1u)) >> 16;
  return (ushort_t)u;
}

// async global->LDS, 16B per lane. LDS dest must be wave-uniform base; HW adds lane*16.
__device__ inline void gll16(const void* g, void* l) {
  __builtin_amdgcn_global_load_lds(
      (__attribute__((address_space(1))) void*)(uintptr_t)g,
      (__attribute__((address_space(3))) void*)(uint32_t)(uintptr_t)l,
      16, 0, 0);
}

__global__ void cast_bf16(const float* __restrict__ in, ushort_t* __restrict__ out,
                          int n4, float scale) {
  int i = blockIdx.x * blockDim.x + threadIdx.x;
  int st = gridDim.x * blockDim.x;
  for (; i < n4; i += st) {
    float4 v = reinterpret_cast<const float4*>(in)[i];
    ushort4 o;
    o.x = f2bf(v.x * scale);
    o.y = f2bf(v.y * scale);
    o.z = f2bf(v.z * scale);
    o.w = f2bf(v.w * scale);
    reinterpret_cast<ushort4*>(out)[i] = o;
  }
}

// All 4 weight matrices in one launch; out = Wq*s | Wk | Wv | Wo contiguous.
__global__ void cast_w4(const float* __restrict__ w0, const float* __restrict__ w1,
                        const float* __restrict__ w2, const float* __restrict__ w3,
                        ushort_t* __restrict__ out, float s0) {
  const int i = blockIdx.x * 256 + threadIdx.x;
  const int which = i >> 18;
  const float* src = which == 0 ? w0 : which == 1 ? w1 : which == 2 ? w2 : w3;
  const float sc = which == 0 ? s0 : 1.0f;
  float4 v = reinterpret_cast<const float4*>(src)[i & 0x3FFFF];
  ushort4 o;
  o.x = f2bf(v.x * sc);
  o.y = f2bf(v.y * sc);
  o.z = f2bf(v.z * sc);
  o.w = f2bf(v.w * sc);
  reinterpret_cast<ushort4*>(out)[i] = o;
}

// ---------------- 8-wave GEMM template: C = A[8192,1024] * B[N,1024]^T
// m201 phase order: ds_read BEFORE barrier, lgkmcnt(0) after -> read latency hides
// under barrier + other waves' MFMA. Trailing vmcnt(0) guards the buffer swap.
#define MFMA16(A_, B_, C_) __builtin_amdgcn_mfma_f32_16x16x32_bf16(A_, B_, C_, 0, 0, 0)

template <int MF, int NF, int NTN, int LDC, bool F32OUT>
__global__ __launch_bounds__(512, 2) void gemm8p(const ushort_t* __restrict__ A,
                                                 const ushort_t* __restrict__ B,
                                                 void* __restrict__ C) {
  constexpr int BM = MF * 32;
  constexpr int BN = NF * 64;
  constexpr int NA = BM / 64;        // gll16 per thread for A-tile
  constexpr int NB = BN / 64;        // gll16 per thread for B-tile
  constexpr int AU = BM * 64;        // u16 per A buffer
  constexpr int BUF = AU + BN * 64;  // u16 per (A|B) buffer
  constexpr int NWG = (8192 / BM) * NTN;
  __shared__ __attribute__((aligned(16))) ushort_t smem[2 * BUF];

  const int tid = threadIdx.x;
  const int lane = tid & 63;
  const int w = tid >> 6;
  const int wm = w >> 2, wn = w & 3;

  // XCD-aware bijective swizzle (NWG % 8 == 0), row-major tiles.
  const int bid = blockIdx.x;
  const int swz = (bid & 7) * (NWG / 8) + (bid >> 3);
  const int m0 = (swz / NTN) * BM;
  const int n0 = (swz % NTN) * BN;

  // staging: thread covers row (tid>>3), phys 16B chunk (tid&7); source col
  // pre-swizzled so phys LDS stays linear (rule #21: same involution both sides).
  const int scol = ((tid & 7) ^ ((tid >> 3) & 7)) * 8;
  const ushort_t* gA = A + (size_t)(m0 + (tid >> 3)) * 1024 + scol;
  const ushort_t* gB = B + (size_t)(n0 + (tid >> 3)) * 1024 + scol;

  // read offsets (u16 units): row*64 + ((k-chunk)*8 ^ (row&7)*8)
  const int lr = lane & 15;
  const int hi = lane >> 4;
  const int arow = (wm * MF * 16 + lr) * 64;
  const int brow = AU + (wn * NF * 16 + lr) * 64;
  const int cx0 = (hi * 8) ^ ((lane & 7) << 3);
  const int cx1 = cx0 ^ 32;

  f32x4 acc[MF][NF] = {};
  bf16x8 a[MF / 2][2], b[NF][2];

  auto stageA = [&](int wbu, int sk) __attribute__((always_inline)) {
#pragma unroll
    for (int i = 0; i < NA; ++i)
      gll16(gA + i * 65536 + sk, &smem[wbu + i * 4096 + (w << 9)]);
  };
  auto stageB = [&](int wbu, int sk) __attribute__((always_inline)) {
#pragma unroll
    for (int i = 0; i < NB; ++i)
      gll16(gB + i * 65536 + sk, &smem[wbu + AU + i * 4096 + (w << 9)]);
  };
  auto rdA = [&](int rbu, int mbase) __attribute__((always_inline)) {
#pragma unroll
    for (int m = 0; m < MF / 2; ++m) {
      const int base = rbu + arow + (mbase + m) * 1024;
      a[m][0] = *(const bf16x8*)&smem[base + cx0];
      a[m][1] = *(const bf16x8*)&smem[base + cx1];
    }
  };
  auto rdB = [&](int rbu) __attribute__((always_inline)) {
#pragma unroll
    for (int n = 0; n < NF; ++n) {
      const int base = rbu + brow + n * 1024;
      b[n][0] = *(const bf16x8*)&smem[base + cx0];
      b[n][1] = *(const bf16x8*)&smem[base + cx1];
    }
  };
  auto mm = [&](int mbase) __attribute__((always_inline)) {
#pragma unroll
    for (int m = 0; m < MF / 2; ++m)
#pragma unroll
      for (int n = 0; n < NF; ++n) {
        acc[mbase + m][n] = MFMA16(a[m][0], b[n][0], acc[mbase + m][n]);
        acc[mbase + m][n] = MFMA16(a[m][1], b[n][1], acc[mbase + m][n]);
      }
  };

  // One K-tile: 2 phases; reads issued pre-barrier; single trailing vmcnt(0).
  auto tile = [&](int rbu, int wbu, int sk, bool pf) __attribute__((always_inline)) {
    // PhA: reads for mm(0) + all staging of tile t+1, then barrier.
    rdA(rbu, 0);
    rdB(rbu);
    if (pf) {
      stageA(wbu, sk);
      stageB(wbu, sk);
    }
    __builtin_amdgcn_s_barrier();
    asm volatile("s_waitcnt lgkmcnt(0)" ::: "memory");
    __builtin_amdgcn_s_setprio(1);
    mm(0);
    __builtin_amdgcn_s_setprio(0);
    __builtin_amdgcn_s_barrier();
    // PhB: reads for mm(MF/2) pre-barrier.
    rdA(rbu, MF / 2);
    __builtin_amdgcn_s_barrier();
    asm volatile("s_waitcnt lgkmcnt(0)" ::: "memory");
    __builtin_amdgcn_s_setprio(1);
    mm(MF / 2);
    __builtin_amdgcn_s_setprio(0);
    if (pf) asm volatile("s_waitcnt vmcnt(0)" ::: "memory");  // tile t+1 landed
    __builtin_amdgcn_s_barrier();
  };

  stageA(0, 0);
  stageB(0, 0);
  asm volatile("s_waitcnt vmcnt(0)" ::: "memory");
  __builtin_amdgcn_s_barrier();
  int sk = 64;
  for (int it = 0; it < 7; ++it) {
    tile(0, BUF, sk, true);
    sk += 64;
    tile(BUF, 0, sk, true);
    sk += 64;
  }
  tile(0, BUF, sk, true);   // t=14 stages tile 15
  tile(BUF, 0, 0, false);   // t=15: drain

  const size_t erow = (size_t)(m0 + wm * MF * 16 + hi * 4);
  const int ecol = n0 + wn * NF * 16 + lr;
#pragma unroll
  for (int mf = 0; mf < MF; ++mf)
#pragma unroll
    for (int nf = 0; nf < NF; ++nf)
#pragma unroll
      for (int r = 0; r < 4; ++r) {
        const size_t idx = (erow + mf * 16 + r) * LDC + ecol + nf * 16;
        if constexpr (F32OUT)
          ((float*)C)[idx] = acc[mf][nf][r];
        else
          ((ushort_t*)C)[idx] = f2bf(acc[mf][nf][r]);
      }
}

// Causal flash attention. QKV [8192,3072] bf16 (Q|K|V), Q pre-scaled by 0.125*log2(e).
// K/V LDS double-buffered: ONE barrier per KV-tile; write phase overlaps nothing.
__global__ __launch_bounds__(256, 2) void attn_fwd(const ushort_t* __restrict__ QKV,
                                                   ushort_t* __restrict__ ctx) {
  const int bid = blockIdx.x;
  const int h = bid & 15;
  const int b = (bid >> 4) & 7;
  const int p = bid >> 7;
  const int tid = threadIdx.x;
  const int lane = tid & 63;
  const int w = tid >> 6;
  const int lr = lane & 15;
  const int lg = lane >> 4;
  const int dk = lg << 3;

  __shared__ __attribute__((aligned(16))) ushort_t Ks[2][64 * 72];
  __shared__ __attribute__((aligned(16))) uint_t VtDw[2][64 * 36];
  __shared__ __attribute__((aligned(16))) ushort_t Pl[4][32 * 72];

  const int kkey = tid >> 2, kdg = tid & 3;
  const int vkp = tid & 31, vdg = tid >> 5;
  const ushort_t* kgbase =
      QKV + ((size_t)(b * 1024 + kkey)) * 3072 + 1024 + h * 64 + kdg * 16;
  const ushort_t* vgbase =
      QKV + ((size_t)(b * 1024 + 2 * vkp)) * 3072 + 2048 + h * 64 + vdg * 8;

  const float FMAX2 = 23.083120654223414f;  // 16 * log2(e)

  for (int pi = 0; pi < 2; ++pi) {
    const int qt = pi ? (7 - p) : p;
    const int q0 = qt << 7;
    const int nt = (qt + 1) << 1;
    const int wrow0 = q0 + w * 32;

    bf16x8 qf[2][2];
#pragma unroll
    for (int i = 0; i < 2; ++i) {
      const ushort_t* qp =
          QKV + ((size_t)(b * 1024 + wrow0 + i * 16 + lr)) * 3072 + h * 64 + dk;
      qf[i][0] = *reinterpret_cast<const bf16x8*>(qp);
      qf[i][1] = *reinterpret_cast<const bf16x8*>(qp + 32);
    }

    f32x4 o[2][4] = {};
    float lsum[2] = {0.f, 0.f};

    uint4 rk0 = *reinterpret_cast<const uint4*>(kgbase);
    uint4 rk1 = *reinterpret_cast<const uint4*>(kgbase + 8);
    uint4 rv0 = *reinterpret_cast<const uint4*>(vgbase);
    uint4 rv1 = *reinterpret_cast<const uint4*>(vgbase + 3072);

    for (int t = 0; t < nt; ++t) {
      const int bsel = t & 1;
      // ---- write phase: regs (loaded last iter) -> LDS buf[t&1]
      asm volatile("s_waitcnt vmcnt(0)" ::: "memory");
      {
        uint_t* kd = reinterpret_cast<uint_t*>(&Ks[bsel][kkey * 72 + kdg * 16]);
        *reinterpret_cast<uint4*>(kd) = rk0;
        *reinterpret_cast<uint4*>(kd + 4) = rk1;
        const ushort_t* e0 = reinterpret_cast<const ushort_t*>(&rv0);
        const ushort_t* e1 = reinterpret_cast<const ushort_t*>(&rv1);
#pragma unroll
        for (int j = 0; j < 8; ++j)
          VtDw[bsel][(vdg * 8 + j) * 36 + vkp] = (uint_t)e0[j] | ((uint_t)e1[j] << 16);
      }
      if (t + 1 < nt) {  // prefetch next tile into regs; lands under compute
        const size_t off = (size_t)(t + 1) * 64 * 3072;
        rk0 = *reinterpret_cast<const uint4*>(kgbase + off);
        rk1 = *reinterpret_cast<const uint4*>(kgbase + off + 8);
        rv0 = *reinterpret_cast<const uint4*>(vgbase + off);
        rv1 = *reinterpret_cast<const uint4*>(vgbase + off + 3072);
      }
      asm volatile("s_waitcnt lgkmcnt(0)" ::: "memory");  // my LDS writes committed
      __builtin_amdgcn_s_barrier();

      const int kb = t << 6;
      if (kb > wrow0 + 31) continue;  // fully masked for this wave

      // ---- QK^T swapped: S^T frag, lane holds keys kb+f*16+lg*4+r for q-row lr
      bf16x8 kf0[4], kf1[4];
#pragma unroll
      for (int f = 0; f < 4; ++f) {
        kf0[f] = *reinterpret_cast<const bf16x8*>(&Ks[bsel][(f * 16 + lr) * 72 + dk]);
        kf1[f] =
            *reinterpret_cast<const bf16x8*>(&Ks[bsel][(f * 16 + lr) * 72 + 32 + dk]);
      }
      f32x4 s[2][4];
#pragma unroll
      for (int i = 0; i < 2; ++i)
#pragma unroll
        for (int f = 0; f < 4; ++f) {
          f32x4 z = {0.f, 0.f, 0.f, 0.f};
          z = __builtin_amdgcn_mfma_f32_16x16x32_bf16(kf0[f], qf[i][0], z, 0, 0, 0);
          s[i][f] = __builtin_amdgcn_mfma_f32_16x16x32_bf16(kf1[f], qf[i][1], z, 0, 0, 0);
        }

      const bool needmask = (kb + 63 > wrow0);
#pragma unroll
      for (int i = 0; i < 2; ++i) {
        const int qr = wrow0 + i * 16 + lr;
#pragma unroll
        for (int f = 0; f < 4; ++f) {
          const int kbase = kb + f * 16 + (lg << 2);
          float p0 = __builtin_amdgcn_exp2f(s[i][f][0] - FMAX2);
          float p1 = __builtin_amdgcn_exp2f(s[i][f][1] - FMAX2);
          float p2 = __builtin_amdgcn_exp2f(s[i][f][2] - FMAX2);
          float p3 = __builtin_amdgcn_exp2f(s[i][f][3] - FMAX2);
          if (needmask) {
            p0 = (kbase + 0 <= qr) ? p0 : 0.f;
            p1 = (kbase + 1 <= qr) ? p1 : 0.f;
            p2 = (kbase + 2 <= qr) ? p2 : 0.f;
            p3 = (kbase + 3 <= qr) ? p3 : 0.f;
          }
          lsum[i] += (p0 + p1) + (p2 + p3);
          ushort4 pk = {f2bf(p0), f2bf(p1), f2bf(p2), f2bf(p3)};
          *reinterpret_cast<ushort4*>(
              &Pl[w][(i * 16 + lr) * 72 + f * 16 + (lg << 2)]) = pk;
        }
      }

      // ---- PV: vb loaded once, reused by both row-frags
      bf16x8 vb[2][4];
#pragma unroll
      for (int kblk = 0; kblk < 2; ++kblk)
#pragma unroll
        for (int fh = 0; fh < 4; ++fh)
          vb[kblk][fh] = *reinterpret_cast<const bf16x8*>(
              &VtDw[bsel][(fh * 16 + lr) * 36 + kblk * 16 + (lg << 2)]);
#pragma unroll
      for (int i = 0; i < 2; ++i)
#pragma unroll
        for (int kblk = 0; kblk < 2; ++kblk) {
          const bf16x8 pa = *reinterpret_cast<const bf16x8*>(
              &Pl[w][(i * 16 + lr) * 72 + kblk * 32 + dk]);
#pragma unroll
          for (int fh = 0; fh < 4; ++fh)
            o[i][fh] = __builtin_amdgcn_mfma_f32_16x16x32_bf16(pa, vb[kblk][fh],
                                                               o[i][fh], 0, 0, 0);
        }
    }

#pragma unroll
    for (int i = 0; i < 2; ++i) {
      float ls = lsum[i];
      ls += __shfl_xor(ls, 16);
      ls += __shfl_xor(ls, 32);
      const float linv = 1.0f / ls;
      const size_t crow = (size_t)(b * 1024 + wrow0 + i * 16 + (lg << 2));
#pragma unroll
      for (int r = 0; r < 4; ++r) {
        const float li = __shfl(linv, (lg << 2) + r);
#pragma unroll
        for (int fh = 0; fh < 4; ++fh)
          ctx[(crow + r) * 1024 + h * 64 + fh * 16 + lr] = f2bf(o[i][fh][r] * li);
      }
    }
  }
}

extern "C" void kernel_launch(void* const* d_in, const int* in_sizes, int n_in,
                              void* d_out, int out_size, void* d_ws, size_t ws_size,
                              hipStream_t stream) {
  const float* x = (const float*)d_in[0];
  const float* Wk = (const float*)d_in[1];
  const float* Wq = (const float*)d_in[2];
  const float* Wv = (const float*)d_in[3];
  const float* Wo = (const float*)d_in[4];

  char* ws = (char*)d_ws;
  ushort_t* xb = (ushort_t*)ws;                  // [8192,1024] bf16 (reused as ctx)
  ushort_t* Wc = (ushort_t*)(ws + (16u << 20));  // Wq*0.125*log2e | Wk | Wv | Wo
  ushort_t* Wob = Wc + 3u * 1024 * 1024;
  ushort_t* QKV = (ushort_t*)(ws + (24u << 20));  // [8192,3072] bf16
  ushort_t* ctx = xb;

  cast_bf16<<<2048, 256, 0, stream>>>(x, xb, (8192 * 1024) / 4, 1.0f);
  cast_w4<<<4096, 256, 0, stream>>>(Wq, Wk, Wv, Wo, Wc, 0.125f * 1.4426950408889634f);

  // QKV: [8192,3072] = xb * Wc^T.  BM=256, BN=192 -> 512 blocks = 2 full rounds.
  gemm8p<8, 3, 16, 3072, false><<<512, 512, 0, stream>>>(xb, Wc, QKV);

  attn_fwd<<<512, 256, 0, stream>>>(QKV, ctx);

  // Out-proj: [8192,1024] = ctx * Wo^T.  BM=128, BN=256 -> 256 blocks = 1 full round.
  gemm8p<4, 4, 4, 1024, true><<<256, 512, 0, stream>>>(ctx, Wob, (float*)d_out);
}